// Round 1
// baseline (377.404 us; speedup 1.0000x reference)
//
#include <hip/hip_runtime.h>
#include <hip/hip_fp16.h>

// Attention: ctx,W = softmax(Q K^T / 32 + mask, padmask) @ V
// B=8, QL=KL=2048, D=1024, fp32 I/O. fp16 MFMA internally (no fp32 MFMA on CDNA4).
#define B_ 8
#define QL_ 2048
#define KL_ 2048
#define D_ 1024

typedef _Float16 f16x8 __attribute__((ext_vector_type(8)));
typedef float f32x4 __attribute__((ext_vector_type(4)));

// LDS tile [128 rows][4 slots of 16B (8 halves)]; XOR-swizzle the slot with
// row&3 so both staging writes and fragment reads are bank-balanced
// (verified by hand: 8 dword-accesses per bank per wave = conflict-free min).
__device__ __forceinline__ int lds_off(int row, int slot) {
  return (row << 6) + (((slot << 4) ^ ((row & 3) << 4)));
}

// ---------------------------------------------------------------- V transpose
// V [b][k][d] fp32  ->  VT [b][d][k] fp16 (in d_ws).  Makes PV a BT-layout GEMM.
__global__ __launch_bounds__(256) void vt_k(const float* __restrict__ V,
                                            _Float16* __restrict__ VT) {
  __shared__ float tile[32][33];
  const int k0 = blockIdx.x * 32, d0 = blockIdx.y * 32, b = blockIdx.z;
  const float* Vb = V + (size_t)b * KL_ * D_;
  _Float16* VTb = VT + (size_t)b * D_ * KL_;
  const int c = threadIdx.x & 31, r = threadIdx.x >> 5;  // 8 rows per sweep
#pragma unroll
  for (int s = 0; s < 4; ++s)
    tile[r + s * 8][c] = Vb[(size_t)(k0 + r + s * 8) * D_ + d0 + c];
  __syncthreads();
#pragma unroll
  for (int s = 0; s < 4; ++s)
    VTb[(size_t)(d0 + r + s * 8) * KL_ + k0 + c] = (_Float16)tile[c][r + s * 8];
}

// ---------------------------------------------------------------- GEMM (both)
// SCORES=true : C[b][q][k] = (sum_d Q[q][d]K[k][d])/32 + mask[q][k], pad -> -1e12
//               A=Q fp32 [2048][1024], B=K fp32 [2048][1024], C=[2048][2048]
// SCORES=false: C[b][q][d] = sum_k W[q][k] VT[d][k]
//               A=W fp32 [2048][2048], B=VT fp16 [1024][2048], C=[2048][1024]
// 128x128 tile, BK=32, 4 waves (2x2), 64x64 per wave = 4x4 MFMA 16x16x32_f16.
// Double-buffered LDS; reg-staged loads with fp32->fp16 conversion.
template <bool SCORES>
__global__ __launch_bounds__(256) void gemm_k(
    const float* __restrict__ Ag, const float* __restrict__ Bf,
    const _Float16* __restrict__ Bh, float* __restrict__ Cg,
    const float* __restrict__ mask, const int* __restrict__ pad) {
  constexpr int Mc = 2048;
  constexpr int Nc = SCORES ? 2048 : 1024;
  constexpr int Kc = SCORES ? 1024 : 2048;
  constexpr int NIT = Kc / 32;

  __shared__ alignas(16) char smem[32768];  // A[2][128][32]h + B[2][128][32]h

  const int t = threadIdx.x;
  const int lane = t & 63;
  const int wid = t >> 6;
  const int wr = wid >> 1, wc = wid & 1;
  const int lo = lane & 15, hi = lane >> 4;
  const int q0 = blockIdx.x * 128, n0 = blockIdx.y * 128;
  const int b = blockIdx.z;

  const float* Ab = Ag + (size_t)b * Mc * Kc;
  const float* Bfb = Bf ? (Bf + (size_t)b * Nc * Kc) : Bf;
  const _Float16* Bhb = Bh ? (Bh + (size_t)b * Nc * Kc) : Bh;

  const int srow = t >> 2;  // staging: thread covers rows srow, srow+64
  const int sc8 = t & 3;    // 8-half slot within the 32-wide k strip

  float4 ra[4];
  float4 rbf[4];
  f16x8 rbh[2];

  auto gload = [&](int kb) {
#pragma unroll
    for (int s = 0; s < 2; ++s) {
      const int row = srow + s * 64;
      const float4* ga = reinterpret_cast<const float4*>(
          Ab + (size_t)(q0 + row) * Kc + kb + sc8 * 8);
      ra[s * 2] = ga[0];
      ra[s * 2 + 1] = ga[1];
      if constexpr (SCORES) {
        const float4* gb = reinterpret_cast<const float4*>(
            Bfb + (size_t)(n0 + row) * Kc + kb + sc8 * 8);
        rbf[s * 2] = gb[0];
        rbf[s * 2 + 1] = gb[1];
      } else {
        rbh[s] = *reinterpret_cast<const f16x8*>(
            Bhb + (size_t)(n0 + row) * Kc + kb + sc8 * 8);
      }
    }
  };

  auto sstore = [&](int buf) {
    char* Ad = smem + buf * 8192;
    char* Bd = smem + 16384 + buf * 8192;
#pragma unroll
    for (int s = 0; s < 2; ++s) {
      const int row = srow + s * 64;
      f16x8 ha;
      ha[0] = (_Float16)ra[s * 2].x;
      ha[1] = (_Float16)ra[s * 2].y;
      ha[2] = (_Float16)ra[s * 2].z;
      ha[3] = (_Float16)ra[s * 2].w;
      ha[4] = (_Float16)ra[s * 2 + 1].x;
      ha[5] = (_Float16)ra[s * 2 + 1].y;
      ha[6] = (_Float16)ra[s * 2 + 1].z;
      ha[7] = (_Float16)ra[s * 2 + 1].w;
      *reinterpret_cast<f16x8*>(Ad + lds_off(row, sc8)) = ha;
      if constexpr (SCORES) {
        f16x8 hb;
        hb[0] = (_Float16)rbf[s * 2].x;
        hb[1] = (_Float16)rbf[s * 2].y;
        hb[2] = (_Float16)rbf[s * 2].z;
        hb[3] = (_Float16)rbf[s * 2].w;
        hb[4] = (_Float16)rbf[s * 2 + 1].x;
        hb[5] = (_Float16)rbf[s * 2 + 1].y;
        hb[6] = (_Float16)rbf[s * 2 + 1].z;
        hb[7] = (_Float16)rbf[s * 2 + 1].w;
        *reinterpret_cast<f16x8*>(Bd + lds_off(row, sc8)) = hb;
      } else {
        *reinterpret_cast<f16x8*>(Bd + lds_off(row, sc8)) = rbh[s];
      }
    }
  };

  f32x4 acc[4][4];
#pragma unroll
  for (int m = 0; m < 4; ++m)
#pragma unroll
    for (int n = 0; n < 4; ++n)
#pragma unroll
      for (int i = 0; i < 4; ++i) acc[m][n][i] = 0.0f;

  gload(0);
  sstore(0);
  __syncthreads();

  for (int it = 0; it < NIT; ++it) {
    const int cur = it & 1;
    if (it + 1 < NIT) gload((it + 1) * 32);  // prefetch next K-strip to regs
    const char* Ad = smem + cur * 8192;
    const char* Bd = smem + 16384 + cur * 8192;
    f16x8 af[4], bfr[4];
#pragma unroll
    for (int m = 0; m < 4; ++m)
      af[m] = *reinterpret_cast<const f16x8*>(
          Ad + lds_off(wr * 64 + m * 16 + lo, hi));
#pragma unroll
    for (int n = 0; n < 4; ++n)
      bfr[n] = *reinterpret_cast<const f16x8*>(
          Bd + lds_off(wc * 64 + n * 16 + lo, hi));
#pragma unroll
    for (int m = 0; m < 4; ++m)
#pragma unroll
      for (int n = 0; n < 4; ++n)
        acc[m][n] = __builtin_amdgcn_mfma_f32_16x16x32_f16(af[m], bfr[n],
                                                           acc[m][n], 0, 0, 0);
    if (it + 1 < NIT) sstore(cur ^ 1);  // write-behind into the other buffer
    __syncthreads();
  }

  // Epilogue.  C layout (verified m89/m91): col = lane&15, row = (lane>>4)*4+i.
  float* Cb = Cg + (size_t)b * Mc * Nc;
  if constexpr (SCORES) {
    const float inv_t = 0.03125f;  // 1/sqrt(1024)
#pragma unroll
    for (int n = 0; n < 4; ++n) {
      const int col = n0 + wc * 64 + n * 16 + lo;
      const int pd = pad[b * Nc + col];
#pragma unroll
      for (int m = 0; m < 4; ++m) {
        const int r0 = q0 + wr * 64 + m * 16 + hi * 4;
#pragma unroll
        for (int i = 0; i < 4; ++i) {
          float s = acc[m][n][i] * inv_t + mask[(size_t)(r0 + i) * Nc + col];
          if (pd) s = -1e12f;  // masked_fill AFTER mask-add (replace, not add)
          Cb[(size_t)(r0 + i) * Nc + col] = s;
        }
      }
    }
  } else {
#pragma unroll
    for (int n = 0; n < 4; ++n) {
      const int col = n0 + wc * 64 + n * 16 + lo;
#pragma unroll
      for (int m = 0; m < 4; ++m) {
        const int r0 = q0 + wr * 64 + m * 16 + hi * 4;
#pragma unroll
        for (int i = 0; i < 4; ++i)
          Cb[(size_t)(r0 + i) * Nc + col] = acc[m][n][i];
      }
    }
  }
}

// ---------------------------------------------------------------- row softmax
// One wave per row of 2048 fp32 (32 VGPR), exact max/sum, in-place normalize.
// Masked entries are -1e12 -> exp underflows to exactly 0 (matches jax).
// All-masked row: m=-1e12, p=1 each -> uniform 1/2048 (also matches jax).
__global__ __launch_bounds__(256) void softmax_k(float* __restrict__ W) {
  const int row = blockIdx.x * 4 + (threadIdx.x >> 6);
  const int lane = threadIdx.x & 63;
  float4* Wr = reinterpret_cast<float4*>(W + (size_t)row * KL_);
  float4 v[8];
#pragma unroll
  for (int s = 0; s < 8; ++s) v[s] = Wr[s * 64 + lane];
  float mx = -3.402823466e38f;
#pragma unroll
  for (int s = 0; s < 8; ++s)
    mx = fmaxf(mx, fmaxf(fmaxf(v[s].x, v[s].y), fmaxf(v[s].z, v[s].w)));
#pragma unroll
  for (int off = 32; off > 0; off >>= 1) mx = fmaxf(mx, __shfl_xor(mx, off));
  float sum = 0.0f;
#pragma unroll
  for (int s = 0; s < 8; ++s) {
    v[s].x = __expf(v[s].x - mx);
    v[s].y = __expf(v[s].y - mx);
    v[s].z = __expf(v[s].z - mx);
    v[s].w = __expf(v[s].w - mx);
    sum += v[s].x + v[s].y + v[s].z + v[s].w;
  }
#pragma unroll
  for (int off = 32; off > 0; off >>= 1) sum += __shfl_xor(sum, off);
  const float inv = 1.0f / sum;
#pragma unroll
  for (int s = 0; s < 8; ++s) {
    float4 o;
    o.x = v[s].x * inv;
    o.y = v[s].y * inv;
    o.z = v[s].z * inv;
    o.w = v[s].w * inv;
    Wr[s * 64 + lane] = o;
  }
}

// ---------------------------------------------------------------- launch
extern "C" void kernel_launch(void* const* d_in, const int* in_sizes, int n_in,
                              void* d_out, int out_size, void* d_ws,
                              size_t ws_size, hipStream_t stream) {
  const float* Q = (const float*)d_in[0];
  const float* K = (const float*)d_in[1];
  const float* V = (const float*)d_in[2];
  const float* mask = (const float*)d_in[3];
  const int* pad = (const int*)d_in[4];

  float* ctx = (float*)d_out;                      // [8][2048][1024]
  float* W = ctx + (size_t)B_ * QL_ * D_;          // [8][2048][2048]
  _Float16* VT = (_Float16*)d_ws;                  // [8][1024][2048] = 32 MiB

  // 1) V -> VT fp16 (transposed) so PV is a BT-layout GEMM
  vt_k<<<dim3(KL_ / 32, D_ / 32, B_), 256, 0, stream>>>(V, VT);
  // 2) raw scores into the weights region (scratch reuse)
  gemm_k<true><<<dim3(QL_ / 128, KL_ / 128, B_), 256, 0, stream>>>(
      Q, K, nullptr, W, mask, pad);
  // 3) exact row softmax in place
  softmax_k<<<dim3(B_ * QL_ / 4), 256, 0, stream>>>(W);
  // 4) ctx = W @ V   (A = W fp32, B = VT fp16)
  gemm_k<false><<<dim3(QL_ / 128, D_ / 128, B_), 256, 0, stream>>>(
      W, nullptr, VT, ctx, nullptr, nullptr);
}

// Round 2
// 354.331 us; speedup vs baseline: 1.0651x; 1.0651x over previous
//
#include <hip/hip_runtime.h>
#include <hip/hip_fp16.h>

// Attention: ctx,W = softmax(Q K^T / 32 + mask, padmask) @ V
// B=8, QL=KL=2048, D=1024, fp32 I/O. fp16 MFMA internally (no fp32 MFMA on CDNA4).
#define B_ 8
#define QL_ 2048
#define KL_ 2048
#define D_ 1024

typedef _Float16 f16x8 __attribute__((ext_vector_type(8)));
typedef _Float16 f16x4 __attribute__((ext_vector_type(4)));
typedef float f32x4 __attribute__((ext_vector_type(4)));

// ---------------------------------------------------------------- async 16B
__device__ __forceinline__ void async16(const void* g, void* l) {
  __builtin_amdgcn_global_load_lds(
      (const __attribute__((address_space(1))) unsigned int*)g,
      (__attribute__((address_space(3))) unsigned int*)l, 16, 0, 0);
}

// ---------------------------------------------------------------- fp32->fp16
__global__ __launch_bounds__(256) void cvt_k(const float* __restrict__ X,
                                             _Float16* __restrict__ Xh) {
  const int i = blockIdx.x * 256 + threadIdx.x;  // one thread per 8 floats
  const float4* src = reinterpret_cast<const float4*>(X);
  float4 a = src[i * 2], b = src[i * 2 + 1];
  f16x8 h;
  h[0] = (_Float16)a.x; h[1] = (_Float16)a.y;
  h[2] = (_Float16)a.z; h[3] = (_Float16)a.w;
  h[4] = (_Float16)b.x; h[5] = (_Float16)b.y;
  h[6] = (_Float16)b.z; h[7] = (_Float16)b.w;
  reinterpret_cast<f16x8*>(Xh)[i] = h;
}

// ---------------------------------------------------------------- V transpose
// V [b][k][d] fp32  ->  VT [b][d][k] fp16 (in d_ws).  Makes PV a BT-layout GEMM.
__global__ __launch_bounds__(256) void vt_k(const float* __restrict__ V,
                                            _Float16* __restrict__ VT) {
  __shared__ float tile[32][33];
  const int k0 = blockIdx.x * 32, d0 = blockIdx.y * 32, b = blockIdx.z;
  const float* Vb = V + (size_t)b * KL_ * D_;
  _Float16* VTb = VT + (size_t)b * D_ * KL_;
  const int c = threadIdx.x & 31, r = threadIdx.x >> 5;  // 8 rows per sweep
#pragma unroll
  for (int s = 0; s < 4; ++s)
    tile[r + s * 8][c] = Vb[(size_t)(k0 + r + s * 8) * D_ + d0 + c];
  __syncthreads();
#pragma unroll
  for (int s = 0; s < 4; ++s)
    VTb[(size_t)(d0 + r + s * 8) * KL_ + k0 + c] = (_Float16)tile[c][r + s * 8];
}

// ---------------------------------------------------------------- fast GEMM
// m97 structure: 128x128 tile, BK=32, 4 waves (2x2), 64x64/wave = 4x4 MFMA
// 16x16x32_f16. Operands fp16 in global; staged via global_load_lds(16B) with
// PRE-SWIZZLED global source (LDS dest must stay lane-linear, m104/m173):
//   LDS[row][slot] holds global 8-half chunk slot^((row>>1)&3).
// Fragment read at slot hi^((row>>1)&3): each 8-lane group of the b128 read
// covers all 8 bank-groups -> conflict-free minimum (derivation in notes).
// SCORES=true : C[b][q][k] = (QK^T)/32 + mask, pad -> -1e12   (Kc=1024)
// SCORES=false: C[b][q][d] = W @ VT^T                         (Kc=2048)
template <bool SCORES>
__global__ __launch_bounds__(256) void fgemm_k(
    const _Float16* __restrict__ Ah, const _Float16* __restrict__ Bh,
    float* __restrict__ Cg, const float* __restrict__ mask,
    const int* __restrict__ pad) {
  constexpr int Mc = 2048;
  constexpr int Nc = SCORES ? 2048 : 1024;
  constexpr int Kc = SCORES ? 1024 : 2048;
  constexpr int NIT = Kc / 32;

  __shared__ alignas(16) _Float16 As[128 * 32];
  __shared__ alignas(16) _Float16 Bs[128 * 32];

  const int t = threadIdx.x;
  const int lane = t & 63;
  const int wid = t >> 6;
  const int wr = wid >> 1, wc = wid & 1;
  const int lo = lane & 15, hi = lane >> 4;
  const int m0 = blockIdx.x * 128, n0 = blockIdx.y * 128;
  const int b = blockIdx.z;

  const _Float16* Ab = Ah + (size_t)b * Mc * Kc;
  const _Float16* Bb = Bh + (size_t)b * Nc * Kc;

  const int srow = t >> 2;   // staging row within a 64-row sweep
  const int dslot = t & 3;   // lane-linear LDS 16B slot within the row

  f32x4 acc[4][4];
#pragma unroll
  for (int m = 0; m < 4; ++m)
#pragma unroll
    for (int n = 0; n < 4; ++n)
#pragma unroll
      for (int i = 0; i < 4; ++i) acc[m][n][i] = 0.0f;

  for (int it = 0; it < NIT; ++it) {
    const int kb = it * 32;
    __syncthreads();  // all ds_reads of previous strip done before overwrite
#pragma unroll
    for (int s = 0; s < 2; ++s) {
      const int row = s * 64 + srow;
      const int gs = dslot ^ ((row >> 1) & 3);  // pre-swizzled source chunk
      async16(Ab + (size_t)(m0 + row) * Kc + kb + gs * 8,
              &As[s * 2048 + wid * 512]);  // wave-uniform base + lane*16
      async16(Bb + (size_t)(n0 + row) * Kc + kb + gs * 8,
              &Bs[s * 2048 + wid * 512]);
    }
    __syncthreads();  // compiler drains vmcnt before barrier -> data visible
    f16x8 af[4], bfr[4];
#pragma unroll
    for (int m = 0; m < 4; ++m) {
      const int r = wr * 64 + m * 16 + lo;
      const int sl = hi ^ ((r >> 1) & 3);
      af[m] = *reinterpret_cast<const f16x8*>(&As[r * 32 + sl * 8]);
    }
#pragma unroll
    for (int n = 0; n < 4; ++n) {
      const int r = wc * 64 + n * 16 + lo;
      const int sl = hi ^ ((r >> 1) & 3);
      bfr[n] = *reinterpret_cast<const f16x8*>(&Bs[r * 32 + sl * 8]);
    }
#pragma unroll
    for (int m = 0; m < 4; ++m)
#pragma unroll
      for (int n = 0; n < 4; ++n)
        acc[m][n] = __builtin_amdgcn_mfma_f32_16x16x32_f16(af[m], bfr[n],
                                                           acc[m][n], 0, 0, 0);
  }

  // Epilogue. C layout (verified): col = lane&15, row = (lane>>4)*4 + i.
  float* Cb = Cg + (size_t)b * Mc * Nc;
  if constexpr (SCORES) {
    const float inv_t = 0.03125f;  // 1/sqrt(1024)
#pragma unroll
    for (int n = 0; n < 4; ++n) {
      const int col = n0 + wc * 64 + n * 16 + lo;
      const int pd = pad[b * Nc + col];
#pragma unroll
      for (int m = 0; m < 4; ++m) {
        const int r0 = m0 + wr * 64 + m * 16 + hi * 4;
#pragma unroll
        for (int i = 0; i < 4; ++i) {
          float s = acc[m][n][i] * inv_t + mask[(size_t)(r0 + i) * Nc + col];
          if (pd) s = -1e12f;  // masked_fill AFTER mask-add (replace, not add)
          Cb[(size_t)(r0 + i) * Nc + col] = s;
        }
      }
    }
  } else {
#pragma unroll
    for (int n = 0; n < 4; ++n) {
      const int col = n0 + wc * 64 + n * 16 + lo;
#pragma unroll
      for (int m = 0; m < 4; ++m) {
        const int r0 = m0 + wr * 64 + m * 16 + hi * 4;
#pragma unroll
        for (int i = 0; i < 4; ++i)
          Cb[(size_t)(r0 + i) * Nc + col] = acc[m][n][i];
      }
    }
  }
}

// ------------------------------------------------- fallback GEMM (round-1)
__device__ __forceinline__ int lds_off(int row, int slot) {
  return (row << 6) + (((slot << 4) ^ ((row & 3) << 4)));
}

template <bool SCORES>
__global__ __launch_bounds__(256) void gemm_k(
    const float* __restrict__ Ag, const float* __restrict__ Bf,
    const _Float16* __restrict__ Bh, float* __restrict__ Cg,
    const float* __restrict__ mask, const int* __restrict__ pad) {
  constexpr int Mc = 2048;
  constexpr int Nc = SCORES ? 2048 : 1024;
  constexpr int Kc = SCORES ? 1024 : 2048;
  constexpr int NIT = Kc / 32;

  __shared__ alignas(16) char smem[32768];

  const int t = threadIdx.x;
  const int lane = t & 63;
  const int wid = t >> 6;
  const int wr = wid >> 1, wc = wid & 1;
  const int lo = lane & 15, hi = lane >> 4;
  const int q0 = blockIdx.x * 128, n0 = blockIdx.y * 128;
  const int b = blockIdx.z;

  const float* Ab = Ag + (size_t)b * Mc * Kc;
  const float* Bfb = Bf ? (Bf + (size_t)b * Nc * Kc) : Bf;
  const _Float16* Bhb = Bh ? (Bh + (size_t)b * Nc * Kc) : Bh;

  const int srow = t >> 2;
  const int sc8 = t & 3;

  float4 ra[4];
  float4 rbf[4];
  f16x8 rbh[2];

  auto gload = [&](int kb) {
#pragma unroll
    for (int s = 0; s < 2; ++s) {
      const int row = srow + s * 64;
      const float4* ga = reinterpret_cast<const float4*>(
          Ab + (size_t)(q0 + row) * Kc + kb + sc8 * 8);
      ra[s * 2] = ga[0];
      ra[s * 2 + 1] = ga[1];
      if constexpr (SCORES) {
        const float4* gb = reinterpret_cast<const float4*>(
            Bfb + (size_t)(n0 + row) * Kc + kb + sc8 * 8);
        rbf[s * 2] = gb[0];
        rbf[s * 2 + 1] = gb[1];
      } else {
        rbh[s] = *reinterpret_cast<const f16x8*>(
            Bhb + (size_t)(n0 + row) * Kc + kb + sc8 * 8);
      }
    }
  };

  auto sstore = [&](int buf) {
    char* Ad = smem + buf * 8192;
    char* Bd = smem + 16384 + buf * 8192;
#pragma unroll
    for (int s = 0; s < 2; ++s) {
      const int row = srow + s * 64;
      f16x8 ha;
      ha[0] = (_Float16)ra[s * 2].x;
      ha[1] = (_Float16)ra[s * 2].y;
      ha[2] = (_Float16)ra[s * 2].z;
      ha[3] = (_Float16)ra[s * 2].w;
      ha[4] = (_Float16)ra[s * 2 + 1].x;
      ha[5] = (_Float16)ra[s * 2 + 1].y;
      ha[6] = (_Float16)ra[s * 2 + 1].z;
      ha[7] = (_Float16)ra[s * 2 + 1].w;
      *reinterpret_cast<f16x8*>(Ad + lds_off(row, sc8)) = ha;
      if constexpr (SCORES) {
        f16x8 hb;
        hb[0] = (_Float16)rbf[s * 2].x;
        hb[1] = (_Float16)rbf[s * 2].y;
        hb[2] = (_Float16)rbf[s * 2].z;
        hb[3] = (_Float16)rbf[s * 2].w;
        hb[4] = (_Float16)rbf[s * 2 + 1].x;
        hb[5] = (_Float16)rbf[s * 2 + 1].y;
        hb[6] = (_Float16)rbf[s * 2 + 1].z;
        hb[7] = (_Float16)rbf[s * 2 + 1].w;
        *reinterpret_cast<f16x8*>(Bd + lds_off(row, sc8)) = hb;
      } else {
        *reinterpret_cast<f16x8*>(Bd + lds_off(row, sc8)) = rbh[s];
      }
    }
  };

  f32x4 acc[4][4];
#pragma unroll
  for (int m = 0; m < 4; ++m)
#pragma unroll
    for (int n = 0; n < 4; ++n)
#pragma unroll
      for (int i = 0; i < 4; ++i) acc[m][n][i] = 0.0f;

  gload(0);
  sstore(0);
  __syncthreads();

  for (int it = 0; it < NIT; ++it) {
    const int cur = it & 1;
    if (it + 1 < NIT) gload((it + 1) * 32);
    const char* Ad = smem + cur * 8192;
    const char* Bd = smem + 16384 + cur * 8192;
    f16x8 af[4], bfr[4];
#pragma unroll
    for (int m = 0; m < 4; ++m)
      af[m] = *reinterpret_cast<const f16x8*>(
          Ad + lds_off(wr * 64 + m * 16 + lo, hi));
#pragma unroll
    for (int n = 0; n < 4; ++n)
      bfr[n] = *reinterpret_cast<const f16x8*>(
          Bd + lds_off(wc * 64 + n * 16 + lo, hi));
#pragma unroll
    for (int m = 0; m < 4; ++m)
#pragma unroll
      for (int n = 0; n < 4; ++n)
        acc[m][n] = __builtin_amdgcn_mfma_f32_16x16x32_f16(af[m], bfr[n],
                                                           acc[m][n], 0, 0, 0);
    if (it + 1 < NIT) sstore(cur ^ 1);
    __syncthreads();
  }

  float* Cb = Cg + (size_t)b * Mc * Nc;
  if constexpr (SCORES) {
    const float inv_t = 0.03125f;
#pragma unroll
    for (int n = 0; n < 4; ++n) {
      const int col = n0 + wc * 64 + n * 16 + lo;
      const int pd = pad[b * Nc + col];
#pragma unroll
      for (int m = 0; m < 4; ++m) {
        const int r0 = q0 + wr * 64 + m * 16 + hi * 4;
#pragma unroll
        for (int i = 0; i < 4; ++i) {
          float s = acc[m][n][i] * inv_t + mask[(size_t)(r0 + i) * Nc + col];
          if (pd) s = -1e12f;
          Cb[(size_t)(r0 + i) * Nc + col] = s;
        }
      }
    }
  } else {
#pragma unroll
    for (int n = 0; n < 4; ++n) {
      const int col = n0 + wc * 64 + n * 16 + lo;
#pragma unroll
      for (int m = 0; m < 4; ++m) {
        const int r0 = q0 + wr * 64 + m * 16 + hi * 4;
#pragma unroll
        for (int i = 0; i < 4; ++i)
          Cb[(size_t)(r0 + i) * Nc + col] = acc[m][n][i];
      }
    }
  }
}

// ---------------------------------------------------------------- row softmax
// One wave per row of 2048 fp32 (32 VGPR), exact max/sum, in-place normalize.
// Masked entries are -1e12 -> exp underflows to exactly 0 (matches jax).
// All-masked row degenerates to uniform 1/2048 (also matches jax).
// Optionally also emits a fp16 copy (PV's A operand for the fast path).
__global__ __launch_bounds__(256) void softmax_k(float* __restrict__ W,
                                                 _Float16* __restrict__ Wh) {
  const int row = blockIdx.x * 4 + (threadIdx.x >> 6);
  const int lane = threadIdx.x & 63;
  float4* Wr = reinterpret_cast<float4*>(W + (size_t)row * KL_);
  float4 v[8];
#pragma unroll
  for (int s = 0; s < 8; ++s) v[s] = Wr[s * 64 + lane];
  float mx = -3.402823466e38f;
#pragma unroll
  for (int s = 0; s < 8; ++s)
    mx = fmaxf(mx, fmaxf(fmaxf(v[s].x, v[s].y), fmaxf(v[s].z, v[s].w)));
#pragma unroll
  for (int off = 32; off > 0; off >>= 1) mx = fmaxf(mx, __shfl_xor(mx, off));
  float sum = 0.0f;
#pragma unroll
  for (int s = 0; s < 8; ++s) {
    v[s].x = __expf(v[s].x - mx);
    v[s].y = __expf(v[s].y - mx);
    v[s].z = __expf(v[s].z - mx);
    v[s].w = __expf(v[s].w - mx);
    sum += v[s].x + v[s].y + v[s].z + v[s].w;
  }
#pragma unroll
  for (int off = 32; off > 0; off >>= 1) sum += __shfl_xor(sum, off);
  const float inv = 1.0f / sum;
  f16x4* Whr = Wh ? reinterpret_cast<f16x4*>(Wh + (size_t)row * KL_) : nullptr;
#pragma unroll
  for (int s = 0; s < 8; ++s) {
    float4 o;
    o.x = v[s].x * inv;
    o.y = v[s].y * inv;
    o.z = v[s].z * inv;
    o.w = v[s].w * inv;
    Wr[s * 64 + lane] = o;
    if (Whr) {
      f16x4 h;
      h[0] = (_Float16)o.x;
      h[1] = (_Float16)o.y;
      h[2] = (_Float16)o.z;
      h[3] = (_Float16)o.w;
      Whr[s * 64 + lane] = h;
    }
  }
}

// ---------------------------------------------------------------- launch
extern "C" void kernel_launch(void* const* d_in, const int* in_sizes, int n_in,
                              void* d_out, int out_size, void* d_ws,
                              size_t ws_size, hipStream_t stream) {
  const float* Q = (const float*)d_in[0];
  const float* K = (const float*)d_in[1];
  const float* V = (const float*)d_in[2];
  const float* mask = (const float*)d_in[3];
  const int* pad = (const int*)d_in[4];

  float* ctx = (float*)d_out;              // [8][2048][1024]
  float* W = ctx + (size_t)B_ * QL_ * D_;  // [8][2048][2048]

  const size_t MB = 1024 * 1024;
  _Float16* VT = (_Float16*)d_ws;  // [8][1024][2048] fp16 = 32 MiB, lives all run

  if (ws_size >= 96 * MB) {
    // fast path: fp16 operands everywhere, global_load_lds GEMMs.
    // region [32,96) MiB: Qh+Kh until scores GEMM, then reused as Wh.
    _Float16* Qh = (_Float16*)((char*)d_ws + 32 * MB);  // 32 MiB
    _Float16* Kh = (_Float16*)((char*)d_ws + 64 * MB);  // 32 MiB
    _Float16* Wh = Qh;                                  // 64 MiB, after reuse

    cvt_k<<<dim3(B_ * QL_ * D_ / 8 / 256), 256, 0, stream>>>(Q, Qh);
    cvt_k<<<dim3(B_ * KL_ * D_ / 8 / 256), 256, 0, stream>>>(K, Kh);
    vt_k<<<dim3(KL_ / 32, D_ / 32, B_), 256, 0, stream>>>(V, VT);
    fgemm_k<true><<<dim3(QL_ / 128, KL_ / 128, B_), 256, 0, stream>>>(
        Qh, Kh, W, mask, pad);
    softmax_k<<<dim3(B_ * QL_ / 4), 256, 0, stream>>>(W, Wh);
    fgemm_k<false><<<dim3(QL_ / 128, D_ / 128, B_), 256, 0, stream>>>(
        Wh, VT, ctx, nullptr, nullptr);
  } else {
    // fallback (round-1 verified path, 32 MiB scratch)
    vt_k<<<dim3(KL_ / 32, D_ / 32, B_), 256, 0, stream>>>(V, VT);
    gemm_k<true><<<dim3(QL_ / 128, KL_ / 128, B_), 256, 0, stream>>>(
        Q, K, nullptr, W, mask, pad);
    softmax_k<<<dim3(B_ * QL_ / 4), 256, 0, stream>>>(W, nullptr);
    gemm_k<false><<<dim3(QL_ / 128, D_ / 128, B_), 256, 0, stream>>>(
        W, nullptr, VT, ctx, nullptr, nullptr);
  }
}